// Round 18
// baseline (333.301 us; speedup 1.0000x reference)
//
#include <hip/hip_runtime.h>

// VQ-VAE VectorQuantizer fwd. K=1024, E=64, N=T*B=65536.
// R18: 3-tier argmin. Tier-1: SINGLE-term bf16 MFMA (coarse; input-rounding
// error RMS ~1.8e-5/score, 6-sigma pair-diff ~1.5e-4; margin GAP1=3e-4)
// -> tier-2 fp32 exact for flagged rows (~10%) -> tier-3 fp64 for fp32-gap
// < GAP2. Replaces the 3-pass bf16-split (R4-R17): MFMA floor 12.4->4.2us,
// stream 5->3KB/tile, x-frag set 64->32 VGPR (residency fits), phase-1
// conversion halves. Ties: equal coarse scores => gap 0 => flagged => exact.
// Scores t = ||c||^2 - 2 x.c; codebook pre-scaled by -2, ||c||^2 in C-init.
// MFMA: A = codebook frag, B = x frag -> D(lane l, reg r) =
// score(code = t*16 + (l>>4)*4 + r, row = base + (l&15)).

#define KC 1024
#define ED 64
#define NR 65536
#define NE (NR * ED)
#define GAP1 3e-4f
#define GAP2 2e-6f

typedef __attribute__((ext_vector_type(8))) short short8;
typedef __attribute__((ext_vector_type(4))) float f32x4;

__device__ __forceinline__ unsigned short bf16rne(float f) {
    unsigned u = __builtin_bit_cast(unsigned, f);
    return (unsigned short)((u + 0x7fffu + ((u >> 16) & 1u)) >> 16);
}

// Pack compact tile records (stride 192 short8 = 3KB) + zero counters.
// Record t: j=0,1 = bf16(-2*c) for e in [0,32),[32,64); elem (g=l>>4,r)
// <-> e = j*32 + g*8 + r (same bijection as the x fragments); j=2: f32x4
// ||c||^2 (reg r <-> code t*16+(l>>4)*4+r) bitcast short8.
__global__ __launch_bounds__(256) void k_pack(const float* __restrict__ cb,
        short8* __restrict__ cbt, unsigned* __restrict__ counts,
        unsigned* __restrict__ flagcnt, unsigned* __restrict__ flagcnt2) {
    const int u = blockIdx.x * 256 + threadIdx.x;
    if (u < 1024) counts[u] = 0u;
    if (u == 1024) *flagcnt = 0u;
    if (u == 1025) *flagcnt2 = 0u;
    if (u >= 64 * 3 * 64) return;
    const int t = u / 192, rem = u % 192, j = rem / 64, l = rem % 64;
    const int g = l >> 4;
    if (j < 2) {
        const int code = t * 16 + (l & 15);
        const float* c = cb + (size_t)code * ED;
        short8 o;
#pragma unroll
        for (int r = 0; r < 8; ++r)
            o[r] = (short)bf16rne(-2.f * c[j * 32 + g * 8 + r]);
        cbt[u] = o;
    } else {
        f32x4 o;
#pragma unroll
        for (int r = 0; r < 4; ++r) {
            const float4* c4 = (const float4*)(cb + (size_t)(t * 16 + g * 4 + r) * ED);
            float s0 = 0.f, s1 = 0.f, s2 = 0.f, s3 = 0.f;
#pragma unroll
            for (int i = 0; i < 16; ++i) {
                const float4 c = c4[i];
                s0 = fmaf(c.x, c.x, s0); s1 = fmaf(c.y, c.y, s1);
                s2 = fmaf(c.z, c.z, s2); s3 = fmaf(c.w, c.w, s3);
            }
            o[r] = (s0 + s1) + (s2 + s3);
        }
        cbt[u] = __builtin_bit_cast(short8, o);
    }
}

// 512 blocks x 512 thr (8 waves = 2 row-groups x 4 K-quarters), 128 rows
// per block, 64 rows/wave. Phase 1: x -> bf16 frags (hi only) into LDS +
// fp32 ||x||^2 partials. Phase 2: wave (rg,kh) holds 8 x-frags (32 VGPR),
// scans tiles [kh*16,+16): 3 loads + 8 MFMA + min-track per tile. Phase 3:
// shfl g-merge; waves 0-1 merge kh slices (ascending k tie-break), write
// idx/fidx/histogram/flag/SSE (d^2 = best + ||x||^2, coarse: err ~1e-9 rel
// on the 4.2M-element mean). Phase 4: cooperative qout gather from fidx.
__global__ __launch_bounds__(512) void k_argmin(
        const float* __restrict__ in, const short8* __restrict__ cbt,
        const float* __restrict__ cb, int* __restrict__ idx,
        float* __restrict__ qout, unsigned* __restrict__ counts,
        unsigned* __restrict__ flagcnt, unsigned* __restrict__ flaglist,
        double* __restrict__ pblk) {
    __shared__ short8 xs[2][8][64];               // 16 KB
    __shared__ float rx2p[4][128];                // 2 KB
    __shared__ float sb[8][4][16], sb2[8][4][16];
    __shared__ int   sk[8][4][16];                // 6 KB
    __shared__ int   fidx[128];
    __shared__ double sred[2];

    const int tid = threadIdx.x;
    const int l = tid & 63;
    const int wid = tid >> 6;                     // 0..7
    const int g = l >> 4;
    const int col = l & 15;
    const int rowBase = blockIdx.x * 128;

    // Phase 1: thread (row=tid&127, ob=tid>>7) converts e in {hh*32+ob*8+j}
    // (16 elems) of its row; ll = ob*16 + (row&15), slot = rt*2 + hh.
    {
        const int row = tid & 127;
        const int ob = tid >> 7;                  // 0..3 (== g of the frag)
        const int rg = row >> 6;
        const int r6 = row & 63;
        const int rt = r6 >> 4;
        const int ll = ob * 16 + (r6 & 15);
        float part = 0.f;
#pragma unroll
        for (int hh = 0; hh < 2; ++hh) {
            short8 H;
#pragma unroll
            for (int j = 0; j < 8; ++j) {
                const float x = in[(size_t)(hh * 32 + ob * 8 + j) * NR + rowBase + row];
                H[j] = (short)bf16rne(x);
                part = fmaf(x, x, part);
            }
            xs[rg][rt * 2 + hh][ll] = H;
        }
        rx2p[ob][row] = part;
    }
    __syncthreads();

    // Phase 2: 8 x-frags to regs (32 VGPR -> resident), simple tile loop.
    const int rg = wid >> 2, kh = wid & 3;
    short8 xq[4][2];
#pragma unroll
    for (int rt = 0; rt < 4; ++rt)
#pragma unroll
        for (int q = 0; q < 2; ++q)
            xq[rt][q] = xs[rg][rt * 2 + q][l];

    float best[4]  = {3.4e38f, 3.4e38f, 3.4e38f, 3.4e38f};
    float best2[4] = {3.4e38f, 3.4e38f, 3.4e38f, 3.4e38f};
    int bestk[4] = {0, 0, 0, 0};

#pragma unroll 2
    for (int tt = 0; tt < 16; ++tt) {
        const int t = kh * 16 + tt;
        const short8* bp = cbt + (size_t)t * 192 + l;
        const short8 b0 = bp[0], b1 = bp[64];
        const f32x4 e4 = __builtin_bit_cast(f32x4, bp[128]);
#pragma unroll
        for (int rt = 0; rt < 4; ++rt) {
            f32x4 acc = e4;
            acc = __builtin_amdgcn_mfma_f32_16x16x32_bf16(b0, xq[rt][0], acc, 0, 0, 0);
            acc = __builtin_amdgcn_mfma_f32_16x16x32_bf16(b1, xq[rt][1], acc, 0, 0, 0);
#pragma unroll
            for (int r = 0; r < 4; ++r) {
                const float v = acc[r];
                const int k = t * 16 + g * 4 + r;
                best2[rt] = fminf(fmaxf(v, best[rt]), best2[rt]);  // med3
                const bool c = v < best[rt];
                bestk[rt] = c ? k : bestk[rt];
                best[rt]  = fminf(v, best[rt]);
            }
        }
    }

    // Phase 3a: intra-wave g-merge; g==0 writes per-(rg,kh) partials.
#pragma unroll
    for (int rt = 0; rt < 4; ++rt) {
        float b = best[rt], b2 = best2[rt]; int k = bestk[rt];
#pragma unroll
        for (int sh = 16; sh <= 32; sh <<= 1) {
            const float ob  = __shfl_xor(b, sh, 64);
            const float ob2 = __shfl_xor(b2, sh, 64);
            const int   ok  = __shfl_xor(k, sh, 64);
            if (ob < b || (ob == b && ok < k)) { b2 = fminf(b, ob2); k = ok; b = ob; }
            else b2 = fminf(b2, ob);
        }
        if (g == 0) { sb[wid][rt][col] = b; sb2[wid][rt][col] = b2; sk[wid][rt][col] = k; }
    }
    __syncthreads();

    // Phase 3b: waves 0-1 (rg=wid) merge the 4 kh slices; finalize rows.
    if (wid < 2) {
        const int rt = l >> 4, c2 = l & 15;
        float b = sb[wid * 4][rt][c2], b2 = sb2[wid * 4][rt][c2];
        int k = sk[wid * 4][rt][c2];
#pragma unroll
        for (int s = 1; s < 4; ++s) {              // ascending k ranges
            const float ob = sb[wid * 4 + s][rt][c2], ob2 = sb2[wid * 4 + s][rt][c2];
            const int ok = sk[wid * 4 + s][rt][c2];
            if (ob < b || (ob == b && ok < k)) { b2 = fminf(b, ob2); k = ok; b = ob; }
            else b2 = fminf(b2, ob);
        }
        const int lrow = wid * 64 + rt * 16 + c2;
        const int row = rowBase + lrow;
        idx[row] = k;
        fidx[lrow] = k;
        atomicAdd(&counts[k], 1u);
        if (b2 - b < GAP1) {
            const unsigned p = atomicAdd(flagcnt, 1u);
            flaglist[p] = (unsigned)row;
        }
        double d2 = (double)b + (double)((rx2p[0][lrow] + rx2p[1][lrow])
                                       + (rx2p[2][lrow] + rx2p[3][lrow]));
#pragma unroll
        for (int off = 32; off > 0; off >>= 1) d2 += __shfl_down(d2, off, 64);
        if (l == 0) sred[wid] = d2;
    }
    __syncthreads();
    if (tid == 0) pblk[blockIdx.x] = sred[0] + sred[1];

    // Phase 4: cooperative gather; lanes cover 64 consecutive rows.
    {
        const int row = tid & 127;
        const int e0 = tid >> 7;                  // 0..3
        const int k = fidx[row];
        const float4* c4 = (const float4*)(cb + (size_t)k * ED + e0 * 16);
#pragma unroll
        for (int j = 0; j < 4; ++j) {
            const float4 v = c4[j];
            qout[(size_t)(e0 * 16 + j * 4 + 0) * NR + rowBase + row] = v.x;
            qout[(size_t)(e0 * 16 + j * 4 + 1) * NR + rowBase + row] = v.y;
            qout[(size_t)(e0 * 16 + j * 4 + 2) * NR + rowBase + row] = v.z;
            qout[(size_t)(e0 * 16 + j * 4 + 3) * NR + rowBase + row] = v.w;
        }
    }
}

// Tier-2: fp32 exact argmin for coarse-flagged rows; one wave per row.
// Fixes idx/counts/qout on change; flags fp32-gap < GAP2 rows for fp64.
__global__ __launch_bounds__(256) void k_exact32(
        const float* __restrict__ in, const float* __restrict__ cb,
        int* __restrict__ idx, float* __restrict__ qout,
        unsigned* __restrict__ counts,
        const unsigned* __restrict__ flagcnt, const unsigned* __restrict__ flaglist,
        unsigned* __restrict__ flagcnt2, unsigned* __restrict__ flaglist2) {
    const unsigned nf = *flagcnt;
    const int l = threadIdx.x & 63;
    const unsigned wave = blockIdx.x * 4u + (unsigned)(threadIdx.x >> 6);
    const unsigned nwave = gridDim.x * 4u;
    for (unsigned i = wave; i < nf; i += nwave) {
        const int row = (int)flaglist[i];
        float x[ED];
#pragma unroll
        for (int e = 0; e < ED; ++e) x[e] = in[(size_t)e * NR + row];
        float best = 3.4e38f, best2 = 3.4e38f; int bestk = 0;
        for (int ci = 0; ci < 16; ++ci) {
            const int k = ci * 64 + l;              // ascending k per lane
            const float4* c4 = (const float4*)(cb + (size_t)k * ED);
            float s0 = 0.f, s1 = 0.f, s2 = 0.f, s3 = 0.f;
            float q0 = 0.f, q1 = 0.f, q2 = 0.f, q3 = 0.f;
#pragma unroll
            for (int e4 = 0; e4 < 16; ++e4) {
                const float4 c = c4[e4];
                s0 = fmaf(c.x, x[e4 * 4 + 0], s0); q0 = fmaf(c.x, c.x, q0);
                s1 = fmaf(c.y, x[e4 * 4 + 1], s1); q1 = fmaf(c.y, c.y, q1);
                s2 = fmaf(c.z, x[e4 * 4 + 2], s2); q2 = fmaf(c.z, c.z, q2);
                s3 = fmaf(c.w, x[e4 * 4 + 3], s3); q3 = fmaf(c.w, c.w, q3);
            }
            const float t = fmaf(-2.f, (s0 + s1) + (s2 + s3),
                                 (q0 + q1) + (q2 + q3));
            const bool c = t < best;
            best2 = c ? best : fminf(best2, t);
            bestk = c ? k : bestk;
            best  = c ? t : best;
        }
#pragma unroll
        for (int sh = 1; sh < 64; sh <<= 1) {
            const float ob  = __shfl_xor(best, sh, 64);
            const float ob2 = __shfl_xor(best2, sh, 64);
            const int   ok  = __shfl_xor(bestk, sh, 64);
            if (ob < best || (ob == best && ok < bestk)) { best2 = fminf(best, ob2); bestk = ok; best = ob; }
            else best2 = fminf(best2, ob);
        }
        const int old = idx[row];                  // uniform across lanes
        if (bestk != old) {
            if (l == 0) {
                idx[row] = bestk;
                atomicSub(&counts[old], 1u);
                atomicAdd(&counts[bestk], 1u);
            }
            qout[(size_t)l * NR + row] = cb[(size_t)bestk * ED + l];
        }
        if (l == 0 && best2 - best < GAP2) {
            const unsigned p = atomicAdd(flagcnt2, 1u);
            flaglist2[p] = (unsigned)row;
        }
    }
}

// Tier-3: fp64 exact argmin for tier-2-flagged rows; one wave per row.
__global__ __launch_bounds__(256) void k_exact64(
        const float* __restrict__ in, const float* __restrict__ cb,
        int* __restrict__ idx, float* __restrict__ qout,
        unsigned* __restrict__ counts,
        const unsigned* __restrict__ flagcnt2, const unsigned* __restrict__ flaglist2) {
    const unsigned nf = *flagcnt2;
    const int l = threadIdx.x & 63;
    const unsigned wave = blockIdx.x * 4u + (unsigned)(threadIdx.x >> 6);
    const unsigned nwave = gridDim.x * 4u;
    for (unsigned i = wave; i < nf; i += nwave) {
        const int row = (int)flaglist2[i];
        float x[ED];
#pragma unroll
        for (int e = 0; e < ED; ++e) x[e] = in[(size_t)e * NR + row];
        double best = 1e300; int bestk = 0;
        for (int ci = 0; ci < 16; ++ci) {
            const int k = ci * 64 + l;
            const float* c = cb + (size_t)k * ED;
            double s = 0.0, e2 = 0.0;
            for (int e = 0; e < ED; ++e) {
                const double cv = (double)c[e];
                e2 = fma(cv, cv, e2);
                s  = fma(cv, (double)x[e], s);
            }
            const double t = fma(-2.0, s, e2);
            if (t < best) { best = t; bestk = k; }
        }
        for (int sh = 1; sh < 64; sh <<= 1) {
            const double ob = __shfl_xor(best, sh, 64);
            const int   ok  = __shfl_xor(bestk, sh, 64);
            if (ob < best || (ob == best && ok < bestk)) { best = ob; bestk = ok; }
        }
        const int old = idx[row];
        if (bestk != old) {
            if (l == 0) {
                idx[row] = bestk;
                atomicSub(&counts[old], 1u);
                atomicAdd(&counts[bestk], 1u);
            }
            qout[(size_t)l * NR + row] = cb[(size_t)bestk * ED + l];
        }
    }
}

// Scalars: entropy from final counts + SSE from 512 per-block partials.
__global__ __launch_bounds__(1024) void k_final(const unsigned* __restrict__ counts,
        const double* __restrict__ pblk, float* __restrict__ out) {
    __shared__ double redE[16], redS[16];
    const int tid = threadIdx.x;
    const double p = (double)counts[tid] * (1.0 / 65536.0);
    double term = p * log(p + 1e-10);
    double s = (tid < 512) ? pblk[tid] : 0.0;
#pragma unroll
    for (int off = 32; off > 0; off >>= 1) {
        term += __shfl_down(term, off, 64);
        s    += __shfl_down(s,    off, 64);
    }
    if ((tid & 63) == 0) { redE[tid >> 6] = term; redS[tid >> 6] = s; }
    __syncthreads();
    if (tid == 0) {
        double e = 0.0, ss = 0.0;
        for (int i = 0; i < 16; ++i) { e += redE[i]; ss += redS[i]; }
        out[1 + NE] = (float)exp(-e);                 // perplexity
        const double m = ss * (1.0 / 4194304.0);      // mean((q-x)^2)
        out[0] = (float)(1.25 * m);                   // (1+beta)*m
    }
}

extern "C" void kernel_launch(void* const* d_in, const int* in_sizes, int n_in,
                              void* d_out, int out_size, void* d_ws, size_t ws_size,
                              hipStream_t stream) {
    (void)in_sizes; (void)n_in; (void)out_size; (void)ws_size;
    const float* in = (const float*)d_in[0];
    const float* cb = (const float*)d_in[1];
    float* out = (float*)d_out;

    // ws layout (dword offsets), strictly disjoint:
    //  [0,1024) counts | [1024] flagcnt | [1025] flagcnt2
    //  [2048,14336)    cbt: 64 tiles x 192 short8 (3KB records)
    //  [83968,149504)  idx | [149504,215040) flaglist | [215040,280576) flaglist2
    //  pblk: 512 f64 at byte 1122304 (8B-aligned, past flaglist2)
    unsigned* counts    = (unsigned*)d_ws;
    unsigned* flagcnt   = (unsigned*)d_ws + 1024;
    unsigned* flagcnt2  = (unsigned*)d_ws + 1025;
    short8*   cbt       = (short8*)((float*)d_ws + 2048);
    int*      idx       = (int*)d_ws + 83968;
    unsigned* flaglist  = (unsigned*)d_ws + 149504;
    unsigned* flaglist2 = (unsigned*)d_ws + 215040;
    double*   pblk      = (double*)((char*)d_ws + 1122304);

    hipLaunchKernelGGL(k_pack,    dim3(48),   dim3(256),  0, stream,
                       cb, cbt, counts, flagcnt, flagcnt2);
    hipLaunchKernelGGL(k_argmin,  dim3(512),  dim3(512),  0, stream,
                       in, cbt, cb, idx, out + 1, counts, flagcnt, flaglist, pblk);
    hipLaunchKernelGGL(k_exact32, dim3(1024), dim3(256),  0, stream,
                       in, cb, idx, out + 1, counts, flagcnt, flaglist,
                       flagcnt2, flaglist2);
    hipLaunchKernelGGL(k_exact64, dim3(128),  dim3(256),  0, stream,
                       in, cb, idx, out + 1, counts, flagcnt2, flaglist2);
    hipLaunchKernelGGL(k_final,   dim3(1),    dim3(1024), 0, stream,
                       counts, pblk, out);
}

// Round 20
// 196.574 us; speedup vs baseline: 1.6955x; 1.6955x over previous
//
#include <hip/hip_runtime.h>

// VQ-VAE VectorQuantizer fwd. K=1024, E=64, N=T*B=65536.
// 3-tier argmin. Tier-1: single-term bf16 MFMA coarse scan (pair-diff err
// sigma ~2.8e-5 incl. correlated x-rounding; GAP1=1.5e-4 ~ 5.4 sigma) ->
// tier-2 fp32 exact (x in LDS, ||c||^2 precomputed) -> tier-3 fp64 for
// fp32-gap < GAP2.
// R20 fix: R19 placed ee INSIDE cbt (cbt is 49152 dwords = [2048,51200),
// not 12288) -> k_pack's ee writes clobbered tiles ~21-22; corrupted bf16
// operands (e.g. 0xD70A ~ -3e14) overflowed fp32 in MFMA -> best=-inf ->
// loss=inf. ee moved to dword 51200; layout re-audited end-to-end.
// Scores t = ||c||^2 - 2 x.c; codebook pre-scaled by -2, ||c||^2 in C-init.
// MFMA: A = codebook frag, B = x frag -> D(lane l, reg r) =
// score(code = t*16 + (l>>4)*4 + r, row = base + (l&15)).

#define KC 1024
#define ED 64
#define NR 65536
#define NE (NR * ED)
#define GAP1 1.5e-4f
#define GAP2 2e-6f

typedef __attribute__((ext_vector_type(8))) short short8;
typedef __attribute__((ext_vector_type(4))) float f32x4;

__device__ __forceinline__ unsigned short bf16rne(float f) {
    unsigned u = __builtin_bit_cast(unsigned, f);
    return (unsigned short)((u + 0x7fffu + ((u >> 16) & 1u)) >> 16);
}

// Pack compact tile records (stride 192 short8 = 3KB) + ee[] + zero ctrs.
// Record t: j=0,1 = bf16(-2*c) for e in [0,32),[32,64); elem (g=l>>4,r)
// <-> e = j*32 + g*8 + r (same bijection as x frags); j=2: f32x4 ||c||^2
// (reg r <-> code t*16+(l>>4)*4+r) bitcast short8. ee[code] = ||c||^2 fp32.
__global__ __launch_bounds__(256) void k_pack(const float* __restrict__ cb,
        short8* __restrict__ cbt, float* __restrict__ ee,
        unsigned* __restrict__ counts,
        unsigned* __restrict__ flagcnt, unsigned* __restrict__ flagcnt2) {
    const int u = blockIdx.x * 256 + threadIdx.x;
    if (u < 1024) counts[u] = 0u;
    if (u == 1024) *flagcnt = 0u;
    if (u == 1025) *flagcnt2 = 0u;
    if (u >= 64 * 3 * 64) return;
    const int t = u / 192, rem = u % 192, j = rem / 64, l = rem % 64;
    const int g = l >> 4;
    if (j < 2) {
        const int code = t * 16 + (l & 15);
        const float* c = cb + (size_t)code * ED;
        short8 o;
#pragma unroll
        for (int r = 0; r < 8; ++r)
            o[r] = (short)bf16rne(-2.f * c[j * 32 + g * 8 + r]);
        cbt[u] = o;
    } else {
        f32x4 o;
#pragma unroll
        for (int r = 0; r < 4; ++r) {
            const float4* c4 = (const float4*)(cb + (size_t)(t * 16 + g * 4 + r) * ED);
            float s0 = 0.f, s1 = 0.f, s2 = 0.f, s3 = 0.f;
#pragma unroll
            for (int i = 0; i < 16; ++i) {
                const float4 c = c4[i];
                s0 = fmaf(c.x, c.x, s0); s1 = fmaf(c.y, c.y, s1);
                s2 = fmaf(c.z, c.z, s2); s3 = fmaf(c.w, c.w, s3);
            }
            o[r] = (s0 + s1) + (s2 + s3);
            ee[t * 16 + g * 4 + r] = o[r];   // 16 threads write same value
        }
        cbt[u] = __builtin_bit_cast(short8, o);
    }
}

// 512 blocks x 512 thr (8 waves = 2 row-groups x 4 K-quarters), 128 rows
// per block, 64 rows/wave. Phase 1: x -> bf16 frags (hi only) into LDS +
// fp32 ||x||^2 partials. Phase 2: wave (rg,kh) scans tiles [kh*16,+16):
// 3 loads + 8 MFMA + min-track per tile. Phase 3: shfl g-merge; waves 0-1
// merge kh slices (ascending k tie-break), write idx/fidx/histogram/flag/
// SSE (d^2 = best + ||x||^2). Phase 4: cooperative qout gather from fidx.
__global__ __launch_bounds__(512) void k_argmin(
        const float* __restrict__ in, const short8* __restrict__ cbt,
        const float* __restrict__ cb, int* __restrict__ idx,
        float* __restrict__ qout, unsigned* __restrict__ counts,
        unsigned* __restrict__ flagcnt, unsigned* __restrict__ flaglist,
        double* __restrict__ pblk) {
    __shared__ short8 xs[2][8][64];               // 16 KB
    __shared__ float rx2p[4][128];                // 2 KB
    __shared__ float sb[8][4][16], sb2[8][4][16];
    __shared__ int   sk[8][4][16];                // 6 KB
    __shared__ int   fidx[128];
    __shared__ double sred[2];

    const int tid = threadIdx.x;
    const int l = tid & 63;
    const int wid = tid >> 6;                     // 0..7
    const int g = l >> 4;
    const int col = l & 15;
    const int rowBase = blockIdx.x * 128;

    // Phase 1: thread (row=tid&127, ob=tid>>7) converts e in {hh*32+ob*8+j}
    // (16 elems) of its row; ll = ob*16 + (row&15), slot = rt*2 + hh.
    {
        const int row = tid & 127;
        const int ob = tid >> 7;                  // 0..3 (== g of the frag)
        const int rg = row >> 6;
        const int r6 = row & 63;
        const int rt = r6 >> 4;
        const int ll = ob * 16 + (r6 & 15);
        float part = 0.f;
#pragma unroll
        for (int hh = 0; hh < 2; ++hh) {
            short8 H;
#pragma unroll
            for (int j = 0; j < 8; ++j) {
                const float x = in[(size_t)(hh * 32 + ob * 8 + j) * NR + rowBase + row];
                H[j] = (short)bf16rne(x);
                part = fmaf(x, x, part);
            }
            xs[rg][rt * 2 + hh][ll] = H;
        }
        rx2p[ob][row] = part;
    }
    __syncthreads();

    // Phase 2: 8 x-frags to regs (32 VGPR), simple tile loop.
    const int rg = wid >> 2, kh = wid & 3;
    short8 xq[4][2];
#pragma unroll
    for (int rt = 0; rt < 4; ++rt)
#pragma unroll
        for (int q = 0; q < 2; ++q)
            xq[rt][q] = xs[rg][rt * 2 + q][l];

    float best[4]  = {3.4e38f, 3.4e38f, 3.4e38f, 3.4e38f};
    float best2[4] = {3.4e38f, 3.4e38f, 3.4e38f, 3.4e38f};
    int bestk[4] = {0, 0, 0, 0};

#pragma unroll 2
    for (int tt = 0; tt < 16; ++tt) {
        const int t = kh * 16 + tt;
        const short8* bp = cbt + (size_t)t * 192 + l;
        const short8 b0 = bp[0], b1 = bp[64];
        const f32x4 e4 = __builtin_bit_cast(f32x4, bp[128]);
#pragma unroll
        for (int rt = 0; rt < 4; ++rt) {
            f32x4 acc = e4;
            acc = __builtin_amdgcn_mfma_f32_16x16x32_bf16(b0, xq[rt][0], acc, 0, 0, 0);
            acc = __builtin_amdgcn_mfma_f32_16x16x32_bf16(b1, xq[rt][1], acc, 0, 0, 0);
#pragma unroll
            for (int r = 0; r < 4; ++r) {
                const float v = acc[r];
                const int k = t * 16 + g * 4 + r;
                best2[rt] = fminf(fmaxf(v, best[rt]), best2[rt]);  // med3
                const bool c = v < best[rt];
                bestk[rt] = c ? k : bestk[rt];
                best[rt]  = fminf(v, best[rt]);
            }
        }
    }

    // Phase 3a: intra-wave g-merge; g==0 writes per-(rg,kh) partials.
#pragma unroll
    for (int rt = 0; rt < 4; ++rt) {
        float b = best[rt], b2 = best2[rt]; int k = bestk[rt];
#pragma unroll
        for (int sh = 16; sh <= 32; sh <<= 1) {
            const float ob  = __shfl_xor(b, sh, 64);
            const float ob2 = __shfl_xor(b2, sh, 64);
            const int   ok  = __shfl_xor(k, sh, 64);
            if (ob < b || (ob == b && ok < k)) { b2 = fminf(b, ob2); k = ok; b = ob; }
            else b2 = fminf(b2, ob);
        }
        if (g == 0) { sb[wid][rt][col] = b; sb2[wid][rt][col] = b2; sk[wid][rt][col] = k; }
    }
    __syncthreads();

    // Phase 3b: waves 0-1 (rg=wid) merge the 4 kh slices; finalize rows.
    if (wid < 2) {
        const int rt = l >> 4, c2 = l & 15;
        float b = sb[wid * 4][rt][c2], b2 = sb2[wid * 4][rt][c2];
        int k = sk[wid * 4][rt][c2];
#pragma unroll
        for (int s = 1; s < 4; ++s) {              // ascending k ranges
            const float ob = sb[wid * 4 + s][rt][c2], ob2 = sb2[wid * 4 + s][rt][c2];
            const int ok = sk[wid * 4 + s][rt][c2];
            if (ob < b || (ob == b && ok < k)) { b2 = fminf(b, ob2); k = ok; b = ob; }
            else b2 = fminf(b2, ob);
        }
        const int lrow = wid * 64 + rt * 16 + c2;
        const int row = rowBase + lrow;
        idx[row] = k;
        fidx[lrow] = k;
        atomicAdd(&counts[k], 1u);
        if (b2 - b < GAP1) {
            const unsigned p = atomicAdd(flagcnt, 1u);
            flaglist[p] = (unsigned)row;
        }
        double d2 = (double)b + (double)((rx2p[0][lrow] + rx2p[1][lrow])
                                       + (rx2p[2][lrow] + rx2p[3][lrow]));
#pragma unroll
        for (int off = 32; off > 0; off >>= 1) d2 += __shfl_down(d2, off, 64);
        if (l == 0) sred[wid] = d2;
    }
    __syncthreads();
    if (tid == 0) pblk[blockIdx.x] = sred[0] + sred[1];

    // Phase 4: cooperative gather; lanes cover 64 consecutive rows.
    {
        const int row = tid & 127;
        const int e0 = tid >> 7;                  // 0..3
        const int k = fidx[row];
        const float4* c4 = (const float4*)(cb + (size_t)k * ED + e0 * 16);
#pragma unroll
        for (int j = 0; j < 4; ++j) {
            const float4 v = c4[j];
            qout[(size_t)(e0 * 16 + j * 4 + 0) * NR + rowBase + row] = v.x;
            qout[(size_t)(e0 * 16 + j * 4 + 1) * NR + rowBase + row] = v.y;
            qout[(size_t)(e0 * 16 + j * 4 + 2) * NR + rowBase + row] = v.z;
            qout[(size_t)(e0 * 16 + j * 4 + 3) * NR + rowBase + row] = v.w;
        }
    }
}

// Tier-2: fp32 exact argmin for coarse-flagged rows; one wave per row.
// x staged in LDS (re-read as ds_read_b128 per chunk -- no 64-reg array),
// ||c||^2 from precomputed ee. Fixes idx/counts/qout on change; flags
// fp32-gap < GAP2 rows for fp64.
__global__ __launch_bounds__(256) void k_exact32(
        const float* __restrict__ in, const float* __restrict__ cb,
        const float* __restrict__ ee, int* __restrict__ idx,
        float* __restrict__ qout, unsigned* __restrict__ counts,
        const unsigned* __restrict__ flagcnt, const unsigned* __restrict__ flaglist,
        unsigned* __restrict__ flagcnt2, unsigned* __restrict__ flaglist2) {
    __shared__ float xls[4][64];
    const unsigned nf = *flagcnt;
    const int l = threadIdx.x & 63;
    const int wid = threadIdx.x >> 6;
    const unsigned wave = blockIdx.x * 4u + (unsigned)wid;
    const unsigned nwave = gridDim.x * 4u;
    for (unsigned i = wave; i < nf; i += nwave) {
        const int row = (int)flaglist[i];
        xls[wid][l] = in[(size_t)l * NR + row];   // wave-local; no barrier
        float best = 3.4e38f, best2 = 3.4e38f; int bestk = 0;
        for (int ci = 0; ci < 16; ++ci) {
            const int k = ci * 64 + l;              // ascending k per lane
            const float4* c4 = (const float4*)(cb + (size_t)k * ED);
            const float4* x4 = (const float4*)xls[wid];
            float s0 = 0.f, s1 = 0.f, s2 = 0.f, s3 = 0.f;
#pragma unroll
            for (int e4 = 0; e4 < 16; ++e4) {
                const float4 c = c4[e4];
                const float4 xv = x4[e4];
                s0 = fmaf(c.x, xv.x, s0);
                s1 = fmaf(c.y, xv.y, s1);
                s2 = fmaf(c.z, xv.z, s2);
                s3 = fmaf(c.w, xv.w, s3);
            }
            const float t = fmaf(-2.f, (s0 + s1) + (s2 + s3), ee[k]);
            const bool c = t < best;
            best2 = c ? best : fminf(best2, t);
            bestk = c ? k : bestk;
            best  = c ? t : best;
        }
#pragma unroll
        for (int sh = 1; sh < 64; sh <<= 1) {
            const float ob  = __shfl_xor(best, sh, 64);
            const float ob2 = __shfl_xor(best2, sh, 64);
            const int   ok  = __shfl_xor(bestk, sh, 64);
            if (ob < best || (ob == best && ok < bestk)) { best2 = fminf(best, ob2); bestk = ok; best = ob; }
            else best2 = fminf(best2, ob);
        }
        const int old = idx[row];                  // uniform across lanes
        if (bestk != old) {
            if (l == 0) {
                idx[row] = bestk;
                atomicSub(&counts[old], 1u);
                atomicAdd(&counts[bestk], 1u);
            }
            qout[(size_t)l * NR + row] = cb[(size_t)bestk * ED + l];
        }
        if (l == 0 && best2 - best < GAP2) {
            const unsigned p = atomicAdd(flagcnt2, 1u);
            flaglist2[p] = (unsigned)row;
        }
    }
}

// Tier-3: fp64 exact argmin for tier-2-flagged rows; one wave per row.
__global__ __launch_bounds__(256) void k_exact64(
        const float* __restrict__ in, const float* __restrict__ cb,
        int* __restrict__ idx, float* __restrict__ qout,
        unsigned* __restrict__ counts,
        const unsigned* __restrict__ flagcnt2, const unsigned* __restrict__ flaglist2) {
    const unsigned nf = *flagcnt2;
    const int l = threadIdx.x & 63;
    const unsigned wave = blockIdx.x * 4u + (unsigned)(threadIdx.x >> 6);
    const unsigned nwave = gridDim.x * 4u;
    for (unsigned i = wave; i < nf; i += nwave) {
        const int row = (int)flaglist2[i];
        float x[ED];
#pragma unroll
        for (int e = 0; e < ED; ++e) x[e] = in[(size_t)e * NR + row];
        double best = 1e300; int bestk = 0;
        for (int ci = 0; ci < 16; ++ci) {
            const int k = ci * 64 + l;
            const float* c = cb + (size_t)k * ED;
            double s = 0.0, e2 = 0.0;
            for (int e = 0; e < ED; ++e) {
                const double cv = (double)c[e];
                e2 = fma(cv, cv, e2);
                s  = fma(cv, (double)x[e], s);
            }
            const double t = fma(-2.0, s, e2);
            if (t < best) { best = t; bestk = k; }
        }
        for (int sh = 1; sh < 64; sh <<= 1) {
            const double ob = __shfl_xor(best, sh, 64);
            const int   ok  = __shfl_xor(bestk, sh, 64);
            if (ob < best || (ob == best && ok < bestk)) { best = ob; bestk = ok; }
        }
        const int old = idx[row];
        if (bestk != old) {
            if (l == 0) {
                idx[row] = bestk;
                atomicSub(&counts[old], 1u);
                atomicAdd(&counts[bestk], 1u);
            }
            qout[(size_t)l * NR + row] = cb[(size_t)bestk * ED + l];
        }
    }
}

// Scalars: entropy from final counts + SSE from 512 per-block partials.
__global__ __launch_bounds__(1024) void k_final(const unsigned* __restrict__ counts,
        const double* __restrict__ pblk, float* __restrict__ out) {
    __shared__ double redE[16], redS[16];
    const int tid = threadIdx.x;
    const double p = (double)counts[tid] * (1.0 / 65536.0);
    double term = p * log(p + 1e-10);
    double s = (tid < 512) ? pblk[tid] : 0.0;
#pragma unroll
    for (int off = 32; off > 0; off >>= 1) {
        term += __shfl_down(term, off, 64);
        s    += __shfl_down(s,    off, 64);
    }
    if ((tid & 63) == 0) { redE[tid >> 6] = term; redS[tid >> 6] = s; }
    __syncthreads();
    if (tid == 0) {
        double e = 0.0, ss = 0.0;
        for (int i = 0; i < 16; ++i) { e += redE[i]; ss += redS[i]; }
        out[1 + NE] = (float)exp(-e);                 // perplexity
        const double m = ss * (1.0 / 4194304.0);      // mean((q-x)^2)
        out[0] = (float)(1.25 * m);                   // (1+beta)*m
    }
}

extern "C" void kernel_launch(void* const* d_in, const int* in_sizes, int n_in,
                              void* d_out, int out_size, void* d_ws, size_t ws_size,
                              hipStream_t stream) {
    (void)in_sizes; (void)n_in; (void)out_size; (void)ws_size;
    const float* in = (const float*)d_in[0];
    const float* cb = (const float*)d_in[1];
    float* out = (float*)d_out;

    // ws layout (dword offsets), strictly disjoint -- re-audited:
    //  [0,1024) counts | [1024] flagcnt | [1025] flagcnt2
    //  [2048,51200)    cbt: 64 tiles x 192 short8 x 4 dw = 49152 dw (192KB)
    //  [51200,52224)   ee (f32[1024])        <- was 16384: INSIDE cbt (bug)
    //  [83968,149504)  idx | [149504,215040) flaglist | [215040,280576) flaglist2
    //  [280576,281600) pblk: 512 f64 (byte 1122304, 8B-aligned)
    unsigned* counts    = (unsigned*)d_ws;
    unsigned* flagcnt   = (unsigned*)d_ws + 1024;
    unsigned* flagcnt2  = (unsigned*)d_ws + 1025;
    short8*   cbt       = (short8*)((float*)d_ws + 2048);
    float*    ee        = (float*)d_ws + 51200;
    int*      idx       = (int*)d_ws + 83968;
    unsigned* flaglist  = (unsigned*)d_ws + 149504;
    unsigned* flaglist2 = (unsigned*)d_ws + 215040;
    double*   pblk      = (double*)((char*)d_ws + 1122304);

    hipLaunchKernelGGL(k_pack,    dim3(48),  dim3(256),  0, stream,
                       cb, cbt, ee, counts, flagcnt, flagcnt2);
    hipLaunchKernelGGL(k_argmin,  dim3(512), dim3(512),  0, stream,
                       in, cbt, cb, idx, out + 1, counts, flagcnt, flaglist, pblk);
    hipLaunchKernelGGL(k_exact32, dim3(256), dim3(256),  0, stream,
                       in, cb, ee, idx, out + 1, counts, flagcnt, flaglist,
                       flagcnt2, flaglist2);
    hipLaunchKernelGGL(k_exact64, dim3(128), dim3(256),  0, stream,
                       in, cb, idx, out + 1, counts, flagcnt2, flaglist2);
    hipLaunchKernelGGL(k_final,   dim3(1),   dim3(1024), 0, stream,
                       counts, pblk, out);
}

// Round 21
// 123.689 us; speedup vs baseline: 2.6947x; 1.5893x over previous
//
#include <hip/hip_runtime.h>

// VQ-VAE VectorQuantizer fwd. K=1024, E=64, N=T*B=65536.
// 3-tier argmin. Tier-1: single-term bf16 MFMA coarse scan (pair-diff err
// sigma ~1.4e-5; GAP1=1.5e-4 ~ 10 sigma; measured flag rate ~10% -- the
// top-2 gap of 1024 scores has mean ~1.5e-3, so ~6.5k rows flag) ->
// tier-2 fp32 exact -> tier-3 fp64 for fp32-gap < GAP2.
// R21: tier-2 restructured. R20's exact32 was 128us at 7% VALUBusy / 10%
// occupancy: 1 wave/SIMD, serial per-row scan, zero codebook reuse. Now:
// 4 rows batched per wave (each c-row load feeds 4 dots = 4x intensity),
// 1024-block grid-stride (4096 waves). Everything else identical.
// Scores t = ||c||^2 - 2 x.c; codebook pre-scaled by -2, ||c||^2 in C-init.
// MFMA: A = codebook frag, B = x frag -> D(lane l, reg r) =
// score(code = t*16 + (l>>4)*4 + r, row = base + (l&15)).

#define KC 1024
#define ED 64
#define NR 65536
#define NE (NR * ED)
#define GAP1 1.5e-4f
#define GAP2 2e-6f

typedef __attribute__((ext_vector_type(8))) short short8;
typedef __attribute__((ext_vector_type(4))) float f32x4;

__device__ __forceinline__ unsigned short bf16rne(float f) {
    unsigned u = __builtin_bit_cast(unsigned, f);
    return (unsigned short)((u + 0x7fffu + ((u >> 16) & 1u)) >> 16);
}

// Pack compact tile records (stride 192 short8 = 3KB) + ee[] + zero ctrs.
// Record t: j=0,1 = bf16(-2*c) for e in [0,32),[32,64); elem (g=l>>4,r)
// <-> e = j*32 + g*8 + r (same bijection as x frags); j=2: f32x4 ||c||^2
// (reg r <-> code t*16+(l>>4)*4+r) bitcast short8. ee[code] = ||c||^2 fp32.
__global__ __launch_bounds__(256) void k_pack(const float* __restrict__ cb,
        short8* __restrict__ cbt, float* __restrict__ ee,
        unsigned* __restrict__ counts,
        unsigned* __restrict__ flagcnt, unsigned* __restrict__ flagcnt2) {
    const int u = blockIdx.x * 256 + threadIdx.x;
    if (u < 1024) counts[u] = 0u;
    if (u == 1024) *flagcnt = 0u;
    if (u == 1025) *flagcnt2 = 0u;
    if (u >= 64 * 3 * 64) return;
    const int t = u / 192, rem = u % 192, j = rem / 64, l = rem % 64;
    const int g = l >> 4;
    if (j < 2) {
        const int code = t * 16 + (l & 15);
        const float* c = cb + (size_t)code * ED;
        short8 o;
#pragma unroll
        for (int r = 0; r < 8; ++r)
            o[r] = (short)bf16rne(-2.f * c[j * 32 + g * 8 + r]);
        cbt[u] = o;
    } else {
        f32x4 o;
#pragma unroll
        for (int r = 0; r < 4; ++r) {
            const float4* c4 = (const float4*)(cb + (size_t)(t * 16 + g * 4 + r) * ED);
            float s0 = 0.f, s1 = 0.f, s2 = 0.f, s3 = 0.f;
#pragma unroll
            for (int i = 0; i < 16; ++i) {
                const float4 c = c4[i];
                s0 = fmaf(c.x, c.x, s0); s1 = fmaf(c.y, c.y, s1);
                s2 = fmaf(c.z, c.z, s2); s3 = fmaf(c.w, c.w, s3);
            }
            o[r] = (s0 + s1) + (s2 + s3);
            ee[t * 16 + g * 4 + r] = o[r];   // 16 threads write same value
        }
        cbt[u] = __builtin_bit_cast(short8, o);
    }
}

// 512 blocks x 512 thr (8 waves = 2 row-groups x 4 K-quarters), 128 rows
// per block, 64 rows/wave. Phase 1: x -> bf16 frags (hi only) into LDS +
// fp32 ||x||^2 partials. Phase 2: wave (rg,kh) scans tiles [kh*16,+16):
// 3 loads + 8 MFMA + min-track per tile. Phase 3: shfl g-merge; waves 0-1
// merge kh slices (ascending k tie-break), write idx/fidx/histogram/flag/
// SSE (d^2 = best + ||x||^2). Phase 4: cooperative qout gather from fidx.
__global__ __launch_bounds__(512) void k_argmin(
        const float* __restrict__ in, const short8* __restrict__ cbt,
        const float* __restrict__ cb, int* __restrict__ idx,
        float* __restrict__ qout, unsigned* __restrict__ counts,
        unsigned* __restrict__ flagcnt, unsigned* __restrict__ flaglist,
        double* __restrict__ pblk) {
    __shared__ short8 xs[2][8][64];               // 16 KB
    __shared__ float rx2p[4][128];                // 2 KB
    __shared__ float sb[8][4][16], sb2[8][4][16];
    __shared__ int   sk[8][4][16];                // 6 KB
    __shared__ int   fidx[128];
    __shared__ double sred[2];

    const int tid = threadIdx.x;
    const int l = tid & 63;
    const int wid = tid >> 6;                     // 0..7
    const int g = l >> 4;
    const int col = l & 15;
    const int rowBase = blockIdx.x * 128;

    // Phase 1: thread (row=tid&127, ob=tid>>7) converts e in {hh*32+ob*8+j}
    // (16 elems) of its row; ll = ob*16 + (row&15), slot = rt*2 + hh.
    {
        const int row = tid & 127;
        const int ob = tid >> 7;                  // 0..3 (== g of the frag)
        const int rg = row >> 6;
        const int r6 = row & 63;
        const int rt = r6 >> 4;
        const int ll = ob * 16 + (r6 & 15);
        float part = 0.f;
#pragma unroll
        for (int hh = 0; hh < 2; ++hh) {
            short8 H;
#pragma unroll
            for (int j = 0; j < 8; ++j) {
                const float x = in[(size_t)(hh * 32 + ob * 8 + j) * NR + rowBase + row];
                H[j] = (short)bf16rne(x);
                part = fmaf(x, x, part);
            }
            xs[rg][rt * 2 + hh][ll] = H;
        }
        rx2p[ob][row] = part;
    }
    __syncthreads();

    // Phase 2: 8 x-frags to regs (32 VGPR), simple tile loop.
    const int rg = wid >> 2, kh = wid & 3;
    short8 xq[4][2];
#pragma unroll
    for (int rt = 0; rt < 4; ++rt)
#pragma unroll
        for (int q = 0; q < 2; ++q)
            xq[rt][q] = xs[rg][rt * 2 + q][l];

    float best[4]  = {3.4e38f, 3.4e38f, 3.4e38f, 3.4e38f};
    float best2[4] = {3.4e38f, 3.4e38f, 3.4e38f, 3.4e38f};
    int bestk[4] = {0, 0, 0, 0};

#pragma unroll 2
    for (int tt = 0; tt < 16; ++tt) {
        const int t = kh * 16 + tt;
        const short8* bp = cbt + (size_t)t * 192 + l;
        const short8 b0 = bp[0], b1 = bp[64];
        const f32x4 e4 = __builtin_bit_cast(f32x4, bp[128]);
#pragma unroll
        for (int rt = 0; rt < 4; ++rt) {
            f32x4 acc = e4;
            acc = __builtin_amdgcn_mfma_f32_16x16x32_bf16(b0, xq[rt][0], acc, 0, 0, 0);
            acc = __builtin_amdgcn_mfma_f32_16x16x32_bf16(b1, xq[rt][1], acc, 0, 0, 0);
#pragma unroll
            for (int r = 0; r < 4; ++r) {
                const float v = acc[r];
                const int k = t * 16 + g * 4 + r;
                best2[rt] = fminf(fmaxf(v, best[rt]), best2[rt]);  // med3
                const bool c = v < best[rt];
                bestk[rt] = c ? k : bestk[rt];
                best[rt]  = fminf(v, best[rt]);
            }
        }
    }

    // Phase 3a: intra-wave g-merge; g==0 writes per-(rg,kh) partials.
#pragma unroll
    for (int rt = 0; rt < 4; ++rt) {
        float b = best[rt], b2 = best2[rt]; int k = bestk[rt];
#pragma unroll
        for (int sh = 16; sh <= 32; sh <<= 1) {
            const float ob  = __shfl_xor(b, sh, 64);
            const float ob2 = __shfl_xor(b2, sh, 64);
            const int   ok  = __shfl_xor(k, sh, 64);
            if (ob < b || (ob == b && ok < k)) { b2 = fminf(b, ob2); k = ok; b = ob; }
            else b2 = fminf(b2, ob);
        }
        if (g == 0) { sb[wid][rt][col] = b; sb2[wid][rt][col] = b2; sk[wid][rt][col] = k; }
    }
    __syncthreads();

    // Phase 3b: waves 0-1 (rg=wid) merge the 4 kh slices; finalize rows.
    if (wid < 2) {
        const int rt = l >> 4, c2 = l & 15;
        float b = sb[wid * 4][rt][c2], b2 = sb2[wid * 4][rt][c2];
        int k = sk[wid * 4][rt][c2];
#pragma unroll
        for (int s = 1; s < 4; ++s) {              // ascending k ranges
            const float ob = sb[wid * 4 + s][rt][c2], ob2 = sb2[wid * 4 + s][rt][c2];
            const int ok = sk[wid * 4 + s][rt][c2];
            if (ob < b || (ob == b && ok < k)) { b2 = fminf(b, ob2); k = ok; b = ob; }
            else b2 = fminf(b2, ob);
        }
        const int lrow = wid * 64 + rt * 16 + c2;
        const int row = rowBase + lrow;
        idx[row] = k;
        fidx[lrow] = k;
        atomicAdd(&counts[k], 1u);
        if (b2 - b < GAP1) {
            const unsigned p = atomicAdd(flagcnt, 1u);
            flaglist[p] = (unsigned)row;
        }
        double d2 = (double)b + (double)((rx2p[0][lrow] + rx2p[1][lrow])
                                       + (rx2p[2][lrow] + rx2p[3][lrow]));
#pragma unroll
        for (int off = 32; off > 0; off >>= 1) d2 += __shfl_down(d2, off, 64);
        if (l == 0) sred[wid] = d2;
    }
    __syncthreads();
    if (tid == 0) pblk[blockIdx.x] = sred[0] + sred[1];

    // Phase 4: cooperative gather; lanes cover 64 consecutive rows.
    {
        const int row = tid & 127;
        const int e0 = tid >> 7;                  // 0..3
        const int k = fidx[row];
        const float4* c4 = (const float4*)(cb + (size_t)k * ED + e0 * 16);
#pragma unroll
        for (int j = 0; j < 4; ++j) {
            const float4 v = c4[j];
            qout[(size_t)(e0 * 16 + j * 4 + 0) * NR + rowBase + row] = v.x;
            qout[(size_t)(e0 * 16 + j * 4 + 1) * NR + rowBase + row] = v.y;
            qout[(size_t)(e0 * 16 + j * 4 + 2) * NR + rowBase + row] = v.z;
            qout[(size_t)(e0 * 16 + j * 4 + 3) * NR + rowBase + row] = v.w;
        }
    }
}

// Tier-2: fp32 exact argmin, 4 flagged rows batched per wave (each c-row
// load feeds 4 dots), 1024-block grid-stride. x in wave-local LDS;
// ||c||^2 from ee. Fixes idx/counts/qout on change; flags fp32-gap < GAP2.
__global__ __launch_bounds__(256) void k_exact32(
        const float* __restrict__ in, const float* __restrict__ cb,
        const float* __restrict__ ee, int* __restrict__ idx,
        float* __restrict__ qout, unsigned* __restrict__ counts,
        const unsigned* __restrict__ flagcnt, const unsigned* __restrict__ flaglist,
        unsigned* __restrict__ flagcnt2, unsigned* __restrict__ flaglist2) {
    __shared__ float xls[4][4][64];
    const unsigned nf = *flagcnt;
    const unsigned nbatch = (nf + 3u) >> 2;
    const int l = threadIdx.x & 63;
    const int wid = threadIdx.x >> 6;
    const unsigned wave = blockIdx.x * 4u + (unsigned)wid;
    const unsigned nwave = gridDim.x * 4u;
    for (unsigned bi = wave; bi < nbatch; bi += nwave) {
        int rows[4]; int nr = 0;
#pragma unroll
        for (int j = 0; j < 4; ++j) {
            const unsigned fi = bi * 4u + j;
            rows[j] = (fi < nf) ? (int)flaglist[fi] : -1;
            if (fi < nf) nr = j + 1;
        }
#pragma unroll
        for (int j = 0; j < 4; ++j)
            xls[wid][j][l] = (rows[j] >= 0) ? in[(size_t)l * NR + rows[j]] : 0.f;

        float best[4]  = {3.4e38f, 3.4e38f, 3.4e38f, 3.4e38f};
        float best2[4] = {3.4e38f, 3.4e38f, 3.4e38f, 3.4e38f};
        int bestk[4] = {0, 0, 0, 0};
        for (int ci = 0; ci < 16; ++ci) {
            const int k = ci * 64 + l;              // ascending k per lane
            const float4* c4 = (const float4*)(cb + (size_t)k * ED);
            float s[4] = {0.f, 0.f, 0.f, 0.f};
#pragma unroll
            for (int e4 = 0; e4 < 16; ++e4) {
                const float4 c = c4[e4];
#pragma unroll
                for (int j = 0; j < 4; ++j) {
                    const float4 xv = ((const float4*)xls[wid][j])[e4];
                    s[j] = fmaf(c.x, xv.x,
                           fmaf(c.y, xv.y,
                           fmaf(c.z, xv.z,
                           fmaf(c.w, xv.w, s[j]))));
                }
            }
            const float ek = ee[k];
#pragma unroll
            for (int j = 0; j < 4; ++j) {
                const float t = fmaf(-2.f, s[j], ek);
                const bool c = t < best[j];
                best2[j] = c ? best[j] : fminf(best2[j], t);
                bestk[j] = c ? k : bestk[j];
                best[j]  = c ? t : best[j];
            }
        }
#pragma unroll
        for (int j = 0; j < 4; ++j) {
            float b = best[j], b2 = best2[j]; int bk = bestk[j];
#pragma unroll
            for (int sh = 1; sh < 64; sh <<= 1) {
                const float ob  = __shfl_xor(b, sh, 64);
                const float ob2 = __shfl_xor(b2, sh, 64);
                const int   ok  = __shfl_xor(bk, sh, 64);
                if (ob < b || (ob == b && ok < bk)) { b2 = fminf(b, ob2); bk = ok; b = ob; }
                else b2 = fminf(b2, ob);
            }
            if (j >= nr) continue;
            const int row = rows[j];
            const int old = idx[row];              // uniform across lanes
            if (bk != old) {
                if (l == 0) {
                    idx[row] = bk;
                    atomicSub(&counts[old], 1u);
                    atomicAdd(&counts[bk], 1u);
                }
                qout[(size_t)l * NR + row] = cb[(size_t)bk * ED + l];
            }
            if (l == 0 && b2 - b < GAP2) {
                const unsigned p = atomicAdd(flagcnt2, 1u);
                flaglist2[p] = (unsigned)row;
            }
        }
    }
}

// Tier-3: fp64 exact argmin for tier-2-flagged rows; one wave per row.
__global__ __launch_bounds__(256) void k_exact64(
        const float* __restrict__ in, const float* __restrict__ cb,
        int* __restrict__ idx, float* __restrict__ qout,
        unsigned* __restrict__ counts,
        const unsigned* __restrict__ flagcnt2, const unsigned* __restrict__ flaglist2) {
    const unsigned nf = *flagcnt2;
    const int l = threadIdx.x & 63;
    const unsigned wave = blockIdx.x * 4u + (unsigned)(threadIdx.x >> 6);
    const unsigned nwave = gridDim.x * 4u;
    for (unsigned i = wave; i < nf; i += nwave) {
        const int row = (int)flaglist2[i];
        float x[ED];
#pragma unroll
        for (int e = 0; e < ED; ++e) x[e] = in[(size_t)e * NR + row];
        double best = 1e300; int bestk = 0;
        for (int ci = 0; ci < 16; ++ci) {
            const int k = ci * 64 + l;
            const float* c = cb + (size_t)k * ED;
            double s = 0.0, e2 = 0.0;
            for (int e = 0; e < ED; ++e) {
                const double cv = (double)c[e];
                e2 = fma(cv, cv, e2);
                s  = fma(cv, (double)x[e], s);
            }
            const double t = fma(-2.0, s, e2);
            if (t < best) { best = t; bestk = k; }
        }
        for (int sh = 1; sh < 64; sh <<= 1) {
            const double ob = __shfl_xor(best, sh, 64);
            const int   ok  = __shfl_xor(bestk, sh, 64);
            if (ob < best || (ob == best && ok < bestk)) { best = ob; bestk = ok; }
        }
        const int old = idx[row];
        if (bestk != old) {
            if (l == 0) {
                idx[row] = bestk;
                atomicSub(&counts[old], 1u);
                atomicAdd(&counts[bestk], 1u);
            }
            qout[(size_t)l * NR + row] = cb[(size_t)bestk * ED + l];
        }
    }
}

// Scalars: entropy from final counts + SSE from 512 per-block partials.
__global__ __launch_bounds__(1024) void k_final(const unsigned* __restrict__ counts,
        const double* __restrict__ pblk, float* __restrict__ out) {
    __shared__ double redE[16], redS[16];
    const int tid = threadIdx.x;
    const double p = (double)counts[tid] * (1.0 / 65536.0);
    double term = p * log(p + 1e-10);
    double s = (tid < 512) ? pblk[tid] : 0.0;
#pragma unroll
    for (int off = 32; off > 0; off >>= 1) {
        term += __shfl_down(term, off, 64);
        s    += __shfl_down(s,    off, 64);
    }
    if ((tid & 63) == 0) { redE[tid >> 6] = term; redS[tid >> 6] = s; }
    __syncthreads();
    if (tid == 0) {
        double e = 0.0, ss = 0.0;
        for (int i = 0; i < 16; ++i) { e += redE[i]; ss += redS[i]; }
        out[1 + NE] = (float)exp(-e);                 // perplexity
        const double m = ss * (1.0 / 4194304.0);      // mean((q-x)^2)
        out[0] = (float)(1.25 * m);                   // (1+beta)*m
    }
}

extern "C" void kernel_launch(void* const* d_in, const int* in_sizes, int n_in,
                              void* d_out, int out_size, void* d_ws, size_t ws_size,
                              hipStream_t stream) {
    (void)in_sizes; (void)n_in; (void)out_size; (void)ws_size;
    const float* in = (const float*)d_in[0];
    const float* cb = (const float*)d_in[1];
    float* out = (float*)d_out;

    // ws layout (dword offsets), strictly disjoint -- audited:
    //  [0,1024) counts | [1024] flagcnt | [1025] flagcnt2
    //  [2048,51200)    cbt: 64 tiles x 192 short8 x 4 dw = 49152 dw (192KB)
    //  [51200,52224)   ee (f32[1024])
    //  [83968,149504)  idx | [149504,215040) flaglist | [215040,280576) flaglist2
    //  [280576,281600) pblk: 512 f64 (byte 1122304, 8B-aligned)
    unsigned* counts    = (unsigned*)d_ws;
    unsigned* flagcnt   = (unsigned*)d_ws + 1024;
    unsigned* flagcnt2  = (unsigned*)d_ws + 1025;
    short8*   cbt       = (short8*)((float*)d_ws + 2048);
    float*    ee        = (float*)d_ws + 51200;
    int*      idx       = (int*)d_ws + 83968;
    unsigned* flaglist  = (unsigned*)d_ws + 149504;
    unsigned* flaglist2 = (unsigned*)d_ws + 215040;
    double*   pblk      = (double*)((char*)d_ws + 1122304);

    hipLaunchKernelGGL(k_pack,    dim3(48),   dim3(256),  0, stream,
                       cb, cbt, ee, counts, flagcnt, flagcnt2);
    hipLaunchKernelGGL(k_argmin,  dim3(512),  dim3(512),  0, stream,
                       in, cbt, cb, idx, out + 1, counts, flagcnt, flaglist, pblk);
    hipLaunchKernelGGL(k_exact32, dim3(1024), dim3(256),  0, stream,
                       in, cb, ee, idx, out + 1, counts, flagcnt, flaglist,
                       flagcnt2, flaglist2);
    hipLaunchKernelGGL(k_exact64, dim3(128),  dim3(256),  0, stream,
                       in, cb, idx, out + 1, counts, flagcnt2, flaglist2);
    hipLaunchKernelGGL(k_final,   dim3(1),    dim3(1024), 0, stream,
                       counts, pblk, out);
}